// Round 5
// baseline (507.563 us; speedup 1.0000x reference)
//
#include <hip/hip_runtime.h>
#include <hip/hip_bf16.h>

typedef unsigned short ushort_t;
typedef __attribute__((ext_vector_type(8))) short short8;
typedef __attribute__((ext_vector_type(4))) short short4v;
typedef __attribute__((ext_vector_type(4))) float float4v;

__device__ __forceinline__ unsigned short f2b(float f) {  // RNE f32->bf16 bits
    unsigned int u = __float_as_uint(f);
    return (unsigned short)((u + 0x7fffu + ((u >> 16) & 1u)) >> 16);
}

#define MFMA(a, b, c) __builtin_amdgcn_mfma_f32_16x16x32_bf16((a), (b), (c), 0, 0, 0)

// ws layout (bf16): wqt[512][128] = Wq^T | wkvt[8][128][128] = per-head [Wk_h^T; Wv_h^T]
// | wot[128][512] = Wo^T.  All are B-operands (B^T row-major, contiguous K).
__global__ void prep_weights(const float* __restrict__ Wq,
                             const float* __restrict__ Wkv,
                             const float* __restrict__ Wo,
                             ushort_t* __restrict__ ws)
{
    int t = blockIdx.x * 256 + threadIdx.x;   // 262144 total
    if (t < 65536) {
        int n = t >> 7, c = t & 127;
        ws[t] = f2b(Wq[c * 512 + n]);
    } else if (t < 196608) {
        int u = t - 65536;
        int h = u >> 14, r = (u >> 7) & 127, c = u & 127;
        float v = (r < 64) ? Wkv[c * 1024 + h * 64 + r]
                           : Wkv[c * 1024 + 512 + h * 64 + (r - 64)];
        ws[t] = f2b(v);
    } else {
        int u = t - 196608;
        int c = u >> 9, n = u & 511;
        ws[t] = f2b(Wo[n * 128 + c]);
    }
}

// LDS (dynamic, 101376 B). All buffers use pow2-chunk rows with XOR swizzle:
// 8-ushort chunk index c stored at physical chunk (c ^ (row & 7)); b128 frag
// reads (row = tile+m) then hit all 32 banks (<=2-way = free).
//   k_u [208][64]  @0       26624 B   k[j][d]; rows 0..63 reused as o[i][d]
//   v_u [64][256]  @26624   32768 B   v^T[dv][j], chunks 26..27 zeroed (j 208..223)
//   sx  [208][128] @0       53248 B   x window staging (dead after frag hoist)
//   p_u [64][256]  @59392   32768 B   exp(sim)[i][j], chunks 26..27 zeroed
//   q_u [64][64]   @92160    8192 B   q[i][d] (pre-scaled by 1/8)
//   s_max @100352 512 B ; s_sum @100864 512 B
__global__ __launch_bounds__(512, 2)
void halo_attn_mfma(const float* __restrict__ xg,
                    const ushort_t* __restrict__ wqt,
                    const ushort_t* __restrict__ wkvt,
                    const ushort_t* __restrict__ wot,
                    const float* __restrict__ bo,
                    float* __restrict__ outg)
{
    extern __shared__ char smem[];
    ushort_t* k_u   = (ushort_t*)(smem);            // [208][64]
    ushort_t* v_u   = (ushort_t*)(smem + 26624);    // [64][256]
    ushort_t* sx_u  = (ushort_t*)(smem);            // [208][128]
    ushort_t* p_u   = (ushort_t*)(smem + 59392);    // [64][256]
    ushort_t* q_u   = (ushort_t*)(smem + 92160);    // [64][64]
    float*    s_max = (float*)(smem + 100352);
    float*    s_sum = (float*)(smem + 100864);
    ushort_t* o_u   = k_u;     // alias: k dead after S, o written in PV

    const int tid  = threadIdx.x;
    const int w    = tid >> 6;       // wave 0..7
    const int lane = tid & 63;
    const int m    = lane & 15;      // MFMA col / A-row lane
    const int quad = lane >> 4;      // MFMA k-group / C row-group

    const int wg  = blockIdx.x;
    const int b   = wg >> 8;
    const int blk = wg & 255;
    const int by = blk >> 4, bx = blk & 15;
    const int y0 = by * 8 - 3, x0 = bx * 8 - 3;

    const short8 zero8 = {0, 0, 0, 0, 0, 0, 0, 0};

    // ---- stage x window [pos][c] bf16, swizzled; pos = wy*14+wx ----
    for (int job = tid; job < 3136; job += 512) {      // 16 c-chunks x 196 pos
        int cc  = job / 196;
        int pos = job - cc * 196;
        int wy = pos / 14;
        int wx = pos - wy * 14;
        int gy = y0 + wy, gx = x0 + wx;
        short8 pk = zero8;
        if ((unsigned)gy < 128u && (unsigned)gx < 128u) {
            const float* xp = xg + ((b * 128 + cc * 8) * 128 + gy) * 128 + gx;
#pragma unroll
            for (int r = 0; r < 8; ++r)
                pk[r] = (short)f2b(xp[r * 16384]);
        }
        *(short8*)(sx_u + pos * 128 + ((cc ^ (pos & 7)) << 3)) = pk;
    }
    for (int t = tid; t < 192; t += 512) {             // zero rows 196..207
        int row = 196 + (t >> 4), cc = t & 15;
        *(short8*)(sx_u + row * 128 + ((cc ^ (row & 7)) << 3)) = zero8;
    }
    __syncthreads();

    // ---- hoist A-fragments (reused across all 8 heads) ----
    short8 xa[2][4];                 // P-kv A: rows jt*16+m, jt = w, w+8
#pragma unroll
    for (int u = 0; u < 2; ++u) {
        int jt = w + 8 * u;
#pragma unroll
        for (int kk = 0; kk < 4; ++kk) {
            xa[u][kk] = zero8;
            if (jt < 13) {
                int row = jt * 16 + m;
                xa[u][kk] = *(const short8*)(sx_u + row * 128 +
                                             (((kk * 4 + quad) ^ (m & 7)) << 3));
            }
        }
    }
    short8 qa[2][4];                 // P-q A: interior rows for it = (w>>2)+2tt
#pragma unroll
    for (int tt = 0; tt < 2; ++tt) {
        int it = (w >> 2) + 2 * tt;
        int i  = it * 16 + m;
        int jq = ((i >> 3) + 3) * 14 + (i & 7) + 3;
#pragma unroll
        for (int kk = 0; kk < 4; ++kk)
            qa[tt][kk] = *(const short8*)(sx_u + jq * 128 +
                                          (((kk * 4 + quad) ^ (jq & 7)) << 3));
    }
    __syncthreads();   // barrier 0: s_x dead; k/v may now overwrite it

    // zero v/p chunks 26..27 (j = 208..223); disjoint from all P/S writes
    for (int t = tid; t < 256; t += 512) {
        int row = t >> 2, cc = 26 + (t & 1);
        ushort_t* base = ((t >> 1) & 1) ? v_u : p_u;
        *(short8*)(base + row * 256 + ((cc ^ (row & 7)) << 3)) = zero8;
    }

    float4v res[4];
#pragma unroll
    for (int i = 0; i < 4; ++i) res[i] = (float4v){0.f, 0.f, 0.f, 0.f};

    for (int h = 0; h < 8; ++h) {
        // ===== P-kv: wave owns jt in {w, w+8}, loops all 8 nt =====
#pragma unroll 1
        for (int nt = 0; nt < 8; ++nt) {
            const ushort_t* bb = wkvt + h * 16384 + (nt * 16 + m) * 128 + quad * 8;
            short8 bfr[4];
#pragma unroll
            for (int kk = 0; kk < 4; ++kk) bfr[kk] = *(const short8*)(bb + kk * 32);
#pragma unroll
            for (int u = 0; u < 2; ++u) {
                int jt = w + 8 * u;
                if (jt < 13) {
                    float4v c = {0.f, 0.f, 0.f, 0.f};
#pragma unroll
                    for (int kk = 0; kk < 4; ++kk) c = MFMA(xa[u][kk], bfr[kk], c);
                    if (nt < 4) {                      // k[j][d]
                        int chunkx = nt * 2 + (m >> 3), inner = m & 7;
#pragma unroll
                        for (int r = 0; r < 4; ++r) {
                            int row = jt * 16 + quad * 4 + r;
                            k_u[row * 64 + ((chunkx ^ (row & 7)) << 3) + inner] = f2b(c[r]);
                        }
                    } else {                           // v^T[dv][j], b64-packed
                        int dv = (nt - 4) * 16 + m;
                        int chunk = jt * 2 + (quad >> 1);
                        short4v pk;
#pragma unroll
                        for (int r = 0; r < 4; ++r) pk[r] = (short)f2b(c[r]);
                        *(short4v*)(v_u + dv * 256 + ((chunk ^ (dv & 7)) << 3) +
                                    (quad & 1) * 4) = pk;
                    }
                }
            }
        }
        // ===== P-q: ntq = w&3 column tile, it = (w>>2)+2tt row tiles =====
        {
            const int ntq = w & 3;
            const ushort_t* bb = wqt + (h * 64 + ntq * 16 + m) * 128 + quad * 8;
            short8 bfr[4];
#pragma unroll
            for (int kk = 0; kk < 4; ++kk) bfr[kk] = *(const short8*)(bb + kk * 32);
#pragma unroll
            for (int tt = 0; tt < 2; ++tt) {
                int it = (w >> 2) + 2 * tt;
                float4v c = {0.f, 0.f, 0.f, 0.f};
#pragma unroll
                for (int kk = 0; kk < 4; ++kk) c = MFMA(qa[tt][kk], bfr[kk], c);
                int chunkx = ntq * 2 + (m >> 3), inner = m & 7;
#pragma unroll
                for (int r = 0; r < 4; ++r) {
                    int row = it * 16 + quad * 4 + r;
                    q_u[row * 64 + ((chunkx ^ (row & 7)) << 3) + inner] =
                        f2b(c[r] * 0.125f);
                }
            }
        }
        __syncthreads();   // barrier 1: k/v/q visible

        // ===== S: sim = q @ k^T, softmax; wave = (it = w&3, half = w>>2) =====
        {
            const int it = w & 3;
            const int half = w >> 2;
            const int jt0 = half ? 7 : 0;
            const int ntile = half ? 6 : 7;
            short8 aq[2];
#pragma unroll
            for (int kk = 0; kk < 2; ++kk)
                aq[kk] = *(const short8*)(q_u + (it * 16 + m) * 64 +
                                          (((kk * 4 + quad) ^ (m & 7)) << 3));
            float sc[7][4];
            int okm = 0;
            float pm[4] = {-3.0e38f, -3.0e38f, -3.0e38f, -3.0e38f};
#pragma unroll
            for (int u = 0; u < 7; ++u) {
                if (u < ntile) {
                    int jt = jt0 + u;
                    float4v c = {0.f, 0.f, 0.f, 0.f};
#pragma unroll
                    for (int kk = 0; kk < 2; ++kk) {
                        short8 bk = *(const short8*)(k_u + (jt * 16 + m) * 64 +
                                                     (((kk * 4 + quad) ^ (m & 7)) << 3));
                        c = MFMA(aq[kk], bk, c);
                    }
                    int j = jt * 16 + m;
                    bool ok = false;
                    if (j < 196) {
                        int wy = j / 14, wx = j - wy * 14;
                        ok = ((unsigned)(y0 + wy) < 128u) && ((unsigned)(x0 + wx) < 128u);
                    }
                    if (ok) {
                        okm |= (1 << u);
#pragma unroll
                        for (int r = 0; r < 4; ++r) pm[r] = fmaxf(pm[r], c[r]);
                    }
#pragma unroll
                    for (int r = 0; r < 4; ++r) sc[u][r] = c[r];
                }
            }
#pragma unroll
            for (int mk = 1; mk < 16; mk <<= 1)
#pragma unroll
                for (int r = 0; r < 4; ++r)
                    pm[r] = fmaxf(pm[r], __shfl_xor(pm[r], mk, 64));
            if (m == 0) {
#pragma unroll
                for (int r = 0; r < 4; ++r)
                    s_max[half * 64 + it * 16 + quad * 4 + r] = pm[r];
            }
            __syncthreads();   // barrier 2: maxes visible
            float m0[4], sm[4];
#pragma unroll
            for (int r = 0; r < 4; ++r) {
                int i = it * 16 + quad * 4 + r;
                m0[r] = fmaxf(s_max[i], s_max[64 + i]);
                sm[r] = 0.f;
            }
#pragma unroll
            for (int u = 0; u < 7; ++u) {
                if (u < ntile) {
                    int j = (jt0 + u) * 16 + m;
                    int chunk = (j >> 3);
                    bool ok = (okm >> u) & 1;
#pragma unroll
                    for (int r = 0; r < 4; ++r) {
                        int i = it * 16 + quad * 4 + r;
                        float p = ok ? __expf(sc[u][r] - m0[r]) : 0.f;
                        sm[r] += p;
                        p_u[i * 256 + ((chunk ^ (i & 7)) << 3) + (j & 7)] = f2b(p);
                    }
                }
            }
#pragma unroll
            for (int mk = 1; mk < 16; mk <<= 1)
#pragma unroll
                for (int r = 0; r < 4; ++r)
                    sm[r] += __shfl_xor(sm[r], mk, 64);
            if (m == 0) {
#pragma unroll
                for (int r = 0; r < 4; ++r)
                    s_sum[half * 64 + it * 16 + quad * 4 + r] = sm[r];
            }
            __syncthreads();   // barrier 3: p + sums visible; k dead
        }

        // ===== PV: o = p @ v (K = 224 zero-padded), normalize -> o_u =====
        {
            const int nt = w & 3;
#pragma unroll
            for (int tt = 0; tt < 2; ++tt) {
                int it = (w >> 2) + 2 * tt;
                float4v c = {0.f, 0.f, 0.f, 0.f};
#pragma unroll
                for (int kk = 0; kk < 7; ++kk) {
                    short8 af = *(const short8*)(p_u + (it * 16 + m) * 256 +
                                                 (((kk * 4 + quad) ^ (m & 7)) << 3));
                    short8 bf = *(const short8*)(v_u + (nt * 16 + m) * 256 +
                                                 (((kk * 4 + quad) ^ (m & 7)) << 3));
                    c = MFMA(af, bf, c);
                }
                int chunkx = nt * 2 + (m >> 3), inner = m & 7;
#pragma unroll
                for (int r = 0; r < 4; ++r) {
                    int i = it * 16 + quad * 4 + r;
                    float rv = 1.f / (s_sum[i] + s_sum[64 + i]);
                    o_u[i * 64 + ((chunkx ^ (i & 7)) << 3) + inner] = f2b(c[r] * rv);
                }
            }
        }
        __syncthreads();   // barrier 4: o visible

        // ===== E: res += o @ Wo_h (C-regs persist across heads) =====
        {
            const int ct = w & 7;
            const ushort_t* bb = wot + (ct * 16 + m) * 512 + h * 64 + quad * 8;
            short8 bw[2];
#pragma unroll
            for (int kk = 0; kk < 2; ++kk) bw[kk] = *(const short8*)(bb + kk * 32);
#pragma unroll
            for (int it = 0; it < 4; ++it) {
                float4v c = res[it];
#pragma unroll
                for (int kk = 0; kk < 2; ++kk) {
                    short8 af = *(const short8*)(o_u + (it * 16 + m) * 64 +
                                                 (((kk * 4 + quad) ^ (m & 7)) << 3));
                    c = MFMA(af, bw[kk], c);
                }
                res[it] = c;
            }
        }
        __syncthreads();   // barrier 5: o reads done before next head's P
    } // heads

    // ---- final: res + bias -> out[b][c][y][x] (fp32) ----
    {
        const int cch = (w & 7) * 16 + m;
        const float bias = bo[cch];
#pragma unroll
        for (int it = 0; it < 4; ++it) {
#pragma unroll
            for (int r = 0; r < 4; ++r) {
                int i = it * 16 + quad * 4 + r;
                int gy = by * 8 + (i >> 3), gx = bx * 8 + (i & 7);
                outg[((b * 128 + cch) * 128 + gy) * 128 + gx] = res[it][r] + bias;
            }
        }
    }
}

extern "C" void kernel_launch(void* const* d_in, const int* in_sizes, int n_in,
                              void* d_out, int out_size, void* d_ws, size_t ws_size,
                              hipStream_t stream) {
    const float* x   = (const float*)d_in[0];
    const float* Wq  = (const float*)d_in[1];
    const float* Wkv = (const float*)d_in[2];
    const float* Wo  = (const float*)d_in[3];
    const float* bo  = (const float*)d_in[4];
    float* out = (float*)d_out;
    ushort_t* ws = (ushort_t*)d_ws;   // needs 512 KB

    prep_weights<<<dim3(1024), dim3(256), 0, stream>>>(Wq, Wkv, Wo, ws);

    (void)hipFuncSetAttribute((const void*)halo_attn_mfma,
                              hipFuncAttributeMaxDynamicSharedMemorySize, 101376);
    halo_attn_mfma<<<dim3(1024), dim3(512), 101376, stream>>>(
        x, ws, ws + 65536, ws + 196608, bo, out);
}